// Round 1
// baseline (1673.636 us; speedup 1.0000x reference)
//
#include <hip/hip_runtime.h>

#define N_ATOMS 100000
#define N_PAIRS 1600000
#define F_A 75
#define F_P 14
#define H 50
#define XS 52   // padded row stride for X1/X2 (13 aligned float4 per row)

// ---------------- kernel 1: atom projections AA, X1, X2 ----------------
// 8 atoms per wave, 4 waves/block => 32 atoms/block. 100000/32 = 3125 blocks.
__global__ __launch_bounds__(256) void k_atom_proj(
    const float* __restrict__ af, const float* __restrict__ W_AA,
    const float* __restrict__ b_AA, const float* __restrict__ W_AP,
    float* __restrict__ AA, float* __restrict__ X1, float* __restrict__ X2)
{
    __shared__ float sWAA[F_A * H];       // 75*50
    __shared__ float sWAP[2 * F_A * H];   // 150*50
    __shared__ float sbAA[H];
    for (int t = threadIdx.x; t < F_A * H; t += 256) sWAA[t] = W_AA[t];
    for (int t = threadIdx.x; t < 2 * F_A * H; t += 256) sWAP[t] = W_AP[t];
    if (threadIdx.x < H) sbAA[threadIdx.x] = b_AA[threadIdx.x];
    __syncthreads();

    const int wave = __builtin_amdgcn_readfirstlane(threadIdx.x >> 6);
    const int lane = threadIdx.x & 63;
    const int h = lane < H ? lane : 0;
    const int base = blockIdx.x * 32 + wave * 8;

    float aa[8], x1[8], x2[8];
    #pragma unroll
    for (int a = 0; a < 8; ++a) { aa[a] = sbAA[h]; x1[a] = 0.f; x2[a] = 0.f; }

    for (int c = 0; c < F_A; ++c) {
        float waa = sWAA[c * H + h];
        float w1  = sWAP[c * H + h];
        float w2  = sWAP[(F_A + c) * H + h];
        #pragma unroll
        for (int a = 0; a < 8; ++a) {
            float f = af[(base + a) * F_A + c];   // wave-uniform -> scalar load
            aa[a] = fmaf(f, waa, aa[a]);
            x1[a] = fmaf(f, w1, x1[a]);
            x2[a] = fmaf(f, w2, x2[a]);
        }
    }
    #pragma unroll
    for (int a = 0; a < 8; ++a) {
        int atom = base + a;
        if (lane < H) {
            AA[atom * H + lane]  = fmaxf(aa[a], 0.f);
            X1[atom * XS + lane] = x1[a];
            X2[atom * XS + lane] = x2[a];
        } else if (lane < XS) {          // zero the pad columns
            X1[atom * XS + lane] = 0.f;
            X2[atom * XS + lane] = 0.f;
        }
    }
}

// ---------------- kernel 2: PA = segment_sum(relu(pf@W_PA+b)) ----------------
// one wave per atom; pair_split is sorted so the segment is a contiguous range.
__global__ __launch_bounds__(256) void k_pa_segsum(
    const float* __restrict__ pf, const int* __restrict__ split,
    const float* __restrict__ W_PA, const float* __restrict__ b_PA,
    float* __restrict__ PA)
{
    const int wave = __builtin_amdgcn_readfirstlane(threadIdx.x >> 6);
    const int lane = threadIdx.x & 63;
    const int h = lane < H ? lane : 0;
    const int atom = blockIdx.x * 4 + wave;

    float w[F_P];
    #pragma unroll
    for (int c = 0; c < F_P; ++c) w[c] = W_PA[c * H + h];
    const float bias = b_PA[h];

    // lower_bound(split, atom) and lower_bound(split, atom+1) — wave-uniform
    int lo = 0, hi = N_PAIRS;
    while (lo < hi) { int mid = (lo + hi) >> 1; if (split[mid] < atom) lo = mid + 1; else hi = mid; }
    const int start = lo;
    hi = N_PAIRS;
    while (lo < hi) { int mid = (lo + hi) >> 1; if (split[mid] <= atom) lo = mid + 1; else hi = mid; }
    const int end = lo;

    float acc = 0.f;
    for (int p = start; p < end; ++p) {
        float v = bias;
        #pragma unroll
        for (int c = 0; c < F_P; ++c) v = fmaf(pf[p * F_P + c], w[c], v);
        acc += fmaxf(v, 0.f);
    }
    if (lane < H) PA[atom * H + lane] = acc;
}

// ---------------- kernel 3: A = relu([AA|PA] @ W_A + b_A) ----------------
__global__ __launch_bounds__(256) void k_atom_out(
    const float* __restrict__ AA, const float* __restrict__ PA,
    const float* __restrict__ W_A, const float* __restrict__ b_A,
    float* __restrict__ outA)
{
    __shared__ float sW[2 * H * H];
    __shared__ float sb[H];
    for (int t = threadIdx.x; t < 2 * H * H; t += 256) sW[t] = W_A[t];
    if (threadIdx.x < H) sb[threadIdx.x] = b_A[threadIdx.x];
    __syncthreads();

    const int wave = __builtin_amdgcn_readfirstlane(threadIdx.x >> 6);
    const int lane = threadIdx.x & 63;
    const int h = lane < H ? lane : 0;
    const int base = blockIdx.x * 32 + wave * 8;

    float acc[8];
    #pragma unroll
    for (int a = 0; a < 8; ++a) acc[a] = sb[h];

    for (int k = 0; k < H; ++k) {
        float wA = sW[k * H + h];
        float wP = sW[(H + k) * H + h];
        #pragma unroll
        for (int a = 0; a < 8; ++a) {
            acc[a] = fmaf(AA[(base + a) * H + k], wA, acc[a]);
            acc[a] = fmaf(PA[(base + a) * H + k], wP, acc[a]);
        }
    }
    #pragma unroll
    for (int a = 0; a < 8; ++a)
        if (lane < H) outA[(base + a) * H + lane] = fmaxf(acc[a], 0.f);
}

// ---------------- kernel 4: P = relu([AP|PP] @ W_P + b_P) ----------------
// one pair per thread. AP reconstructed from gathered X1/X2 rows.
__global__ __launch_bounds__(256) void k_pair_out(
    const float* __restrict__ pf, const int* __restrict__ a2p,
    const float* __restrict__ X1, const float* __restrict__ X2,
    const float* __restrict__ b_AP, const float* __restrict__ W_PP,
    const float* __restrict__ b_PP, const float* __restrict__ W_P,
    const float* __restrict__ b_P, float* __restrict__ outP)
{
    __shared__ float sWpA[XS][XS];   // W_P rows 0..49 (AP part), zero-padded
    __shared__ float sWpP[H][XS];    // W_P rows 50..99 (PP part), col-padded
    __shared__ float sWPP[F_P][H];
    __shared__ float sbAP[XS];
    __shared__ float sbPP[H];
    __shared__ float sbP[H];

    for (int t = threadIdx.x; t < XS * XS; t += 256) {
        int k = t / XS, hh = t % XS;
        (&sWpA[0][0])[t] = (k < H && hh < H) ? W_P[k * H + hh] : 0.f;
    }
    for (int t = threadIdx.x; t < H * XS; t += 256) {
        int h2 = t / XS, hh = t % XS;
        (&sWpP[0][0])[t] = (hh < H) ? W_P[(H + h2) * H + hh] : 0.f;
    }
    for (int t = threadIdx.x; t < F_P * H; t += 256) (&sWPP[0][0])[t] = W_PP[t];
    if (threadIdx.x < H) {
        sbAP[threadIdx.x] = b_AP[threadIdx.x];
        sbPP[threadIdx.x] = b_PP[threadIdx.x];
        sbP[threadIdx.x]  = b_P[threadIdx.x];
    }
    if (threadIdx.x >= H && threadIdx.x < XS) sbAP[threadIdx.x] = 0.f;
    __syncthreads();

    const int p = blockIdx.x * 256 + threadIdx.x;   // 6250*256 == N_PAIRS exactly
    const int2 ij = ((const int2*)a2p)[p];
    const int i = ij.x, j = ij.y;

    float pfr[F_P];
    {
        const float2* src = (const float2*)(pf + (size_t)p * F_P);
        #pragma unroll
        for (int c = 0; c < F_P / 2; ++c) { float2 v = src[c]; pfr[2*c] = v.x; pfr[2*c+1] = v.y; }
    }

    float acc[H];
    #pragma unroll
    for (int hh = 0; hh < H; ++hh) acc[hh] = sbP[hh];

    const float4* x1i = (const float4*)(X1 + (size_t)i * XS);
    const float4* x2i = (const float4*)(X2 + (size_t)i * XS);
    const float4* x1j = (const float4*)(X1 + (size_t)j * XS);
    const float4* x2j = (const float4*)(X2 + (size_t)j * XS);

    for (int kc = 0; kc < XS / 4; ++kc) {
        float4 va = x1i[kc], vb = x2j[kc], vc = x1j[kc], vd = x2i[kc];
        const float* fa = (const float*)&va;
        const float* fb = (const float*)&vb;
        const float* fc = (const float*)&vc;
        const float* fd = (const float*)&vd;
        #pragma unroll
        for (int t = 0; t < 4; ++t) {
            int k = kc * 4 + t;
            float e1 = fa[t] + fb[t] + sbAP[k];
            float e2 = fc[t] + fd[t] + sbAP[k];
            float ap = fmaxf(e1, 0.f) + fmaxf(e2, 0.f);
            #pragma unroll
            for (int hh = 0; hh < H; ++hh)
                acc[hh] = fmaf(ap, sWpA[k][hh], acc[hh]);
        }
    }

    for (int h2 = 0; h2 < H; ++h2) {
        float v = sbPP[h2];
        #pragma unroll
        for (int c = 0; c < F_P; ++c) v = fmaf(pfr[c], sWPP[c][h2], v);
        v = fmaxf(v, 0.f);
        #pragma unroll
        for (int hh = 0; hh < H; ++hh)
            acc[hh] = fmaf(v, sWpP[h2][hh], acc[hh]);
    }

    float* dst = outP + (size_t)p * H;
    #pragma unroll
    for (int hh = 0; hh < H; hh += 2) {
        float2 v; v.x = fmaxf(acc[hh], 0.f); v.y = fmaxf(acc[hh + 1], 0.f);
        *(float2*)(dst + hh) = v;
    }
}

// ---------------- launcher ----------------
extern "C" void kernel_launch(void* const* d_in, const int* in_sizes, int n_in,
                              void* d_out, int out_size, void* d_ws, size_t ws_size,
                              hipStream_t stream) {
    const float* af    = (const float*)d_in[0];
    const float* pfeat = (const float*)d_in[1];
    const int*   split = (const int*)d_in[2];
    const int*   a2p   = (const int*)d_in[3];
    const float* W_AA  = (const float*)d_in[4];
    const float* b_AA  = (const float*)d_in[5];
    const float* W_PA  = (const float*)d_in[6];
    const float* b_PA  = (const float*)d_in[7];
    const float* W_A   = (const float*)d_in[8];
    const float* b_A   = (const float*)d_in[9];
    const float* W_AP  = (const float*)d_in[10];
    const float* b_AP  = (const float*)d_in[11];
    const float* W_PP  = (const float*)d_in[12];
    const float* b_PP  = (const float*)d_in[13];
    const float* W_P   = (const float*)d_in[14];
    const float* b_P   = (const float*)d_in[15];

    float* outA = (float*)d_out;                       // [N_ATOMS, 50]
    float* outP = (float*)d_out + (size_t)N_ATOMS * H; // [N_PAIRS, 50]

    float* ws = (float*)d_ws;
    float* X1 = ws;                              // N_ATOMS*XS
    float* X2 = X1 + (size_t)N_ATOMS * XS;       // N_ATOMS*XS
    float* AA = X2 + (size_t)N_ATOMS * XS;       // N_ATOMS*H
    float* PA = AA + (size_t)N_ATOMS * H;        // N_ATOMS*H

    k_atom_proj<<<N_ATOMS / 32, 256, 0, stream>>>(af, W_AA, b_AA, W_AP, AA, X1, X2);
    k_pa_segsum<<<N_ATOMS / 4, 256, 0, stream>>>(pfeat, split, W_PA, b_PA, PA);
    k_atom_out<<<N_ATOMS / 32, 256, 0, stream>>>(AA, PA, W_A, b_A, outA);
    k_pair_out<<<N_PAIRS / 256, 256, 0, stream>>>(pfeat, a2p, X1, X2,
                                                  b_AP, W_PP, b_PP, W_P, b_P, outP);
}

// Round 2
// 1404.141 us; speedup vs baseline: 1.1919x; 1.1919x over previous
//
#include <hip/hip_runtime.h>

#define N_ATOMS 100000
#define N_PAIRS 1600000
#define F_A 75
#define F_P 14
#define H 50

typedef float f32x2 __attribute__((ext_vector_type(2)));

__device__ inline unsigned short f2bf(float f) {
    unsigned u = __float_as_uint(f);
    u += 0x7fffu + ((u >> 16) & 1u);
    return (unsigned short)(u >> 16);
}
__device__ inline float bfu(unsigned u, int hi) {
    return __uint_as_float(hi ? (u & 0xffff0000u) : (u << 16));
}

// ---------------- kernel 0: row_start[a] = lower_bound(split, a) ----------------
__global__ __launch_bounds__(256) void k_row_starts(
    const int* __restrict__ split, int* __restrict__ row_start)
{
    int p = blockIdx.x * 256 + threadIdx.x;
    if (p >= N_PAIRS) return;
    int s = split[p];
    int sp = (p == 0) ? -1 : split[p - 1];
    for (int a = sp + 1; a <= s; ++a) row_start[a] = p;
    if (p == N_PAIRS - 1)
        for (int a = s + 1; a <= N_ATOMS; ++a) row_start[a] = N_PAIRS;
}

// ---------------- kernel 1: atom projections AA (f32), X (packed bf16) ----------------
// X row layout (128 bf16 = 256B aligned): [0..49]=X1, [50..63]=0, [64..113]=X2, [114..127]=0
__global__ __launch_bounds__(256) void k_atom_proj(
    const float* __restrict__ af, const float* __restrict__ W_AA,
    const float* __restrict__ b_AA, const float* __restrict__ W_AP,
    float* __restrict__ AA, unsigned short* __restrict__ X)
{
    __shared__ float sWAA[F_A * H];
    __shared__ float sWAP[2 * F_A * H];
    __shared__ float sbAA[H];
    for (int t = threadIdx.x; t < F_A * H; t += 256) sWAA[t] = W_AA[t];
    for (int t = threadIdx.x; t < 2 * F_A * H; t += 256) sWAP[t] = W_AP[t];
    if (threadIdx.x < H) sbAA[threadIdx.x] = b_AA[threadIdx.x];
    __syncthreads();

    const int wave = __builtin_amdgcn_readfirstlane(threadIdx.x >> 6);
    const int lane = threadIdx.x & 63;
    const int h = lane < H ? lane : 0;
    const int base = blockIdx.x * 32 + wave * 8;

    float aa[8], x1[8], x2[8];
    #pragma unroll
    for (int a = 0; a < 8; ++a) { aa[a] = sbAA[h]; x1[a] = 0.f; x2[a] = 0.f; }

    for (int c = 0; c < F_A; ++c) {
        float waa = sWAA[c * H + h];
        float w1  = sWAP[c * H + h];
        float w2  = sWAP[(F_A + c) * H + h];
        #pragma unroll
        for (int a = 0; a < 8; ++a) {
            float f = af[(base + a) * F_A + c];
            aa[a] = fmaf(f, waa, aa[a]);
            x1[a] = fmaf(f, w1, x1[a]);
            x2[a] = fmaf(f, w2, x2[a]);
        }
    }
    #pragma unroll
    for (int a = 0; a < 8; ++a) {
        int atom = base + a;
        if (lane < H) AA[(size_t)atom * H + lane] = fmaxf(aa[a], 0.f);
        unsigned short v1 = (lane < H) ? f2bf(x1[a]) : (unsigned short)0;
        unsigned short v2 = (lane < H) ? f2bf(x2[a]) : (unsigned short)0;
        unsigned short* Xrow = X + (size_t)atom * 128;
        Xrow[lane]      = v1;
        Xrow[64 + lane] = v2;
    }
}

// ---------------- kernel 2: PA = segment_sum(relu(pf@W_PA+b)) ----------------
__global__ __launch_bounds__(256) void k_pa_segsum(
    const float* __restrict__ pf, const int* __restrict__ row_start,
    const float* __restrict__ W_PA, const float* __restrict__ b_PA,
    float* __restrict__ PA)
{
    const int wave = __builtin_amdgcn_readfirstlane(threadIdx.x >> 6);
    const int lane = threadIdx.x & 63;
    const int h = lane < H ? lane : 0;
    const int atom = blockIdx.x * 4 + wave;

    float w[F_P];
    #pragma unroll
    for (int c = 0; c < F_P; ++c) w[c] = W_PA[c * H + h];
    const float bias = b_PA[h];

    const int start = row_start[atom];
    const int end   = row_start[atom + 1];

    float acc = 0.f;
    int p = start;
    for (; p + 2 <= end; p += 2) {
        const f32x2* r0 = (const f32x2*)(pf + (size_t)p * F_P);
        const f32x2* r1 = (const f32x2*)(pf + (size_t)(p + 1) * F_P);
        f32x2 v0[7], v1[7];
        #pragma unroll
        for (int c = 0; c < 7; ++c) {
            v0[c] = __builtin_nontemporal_load(r0 + c);
            v1[c] = __builtin_nontemporal_load(r1 + c);
        }
        float s0 = bias, s1 = bias;
        #pragma unroll
        for (int c = 0; c < 7; ++c) {
            s0 = fmaf(v0[c].x, w[2*c], s0); s0 = fmaf(v0[c].y, w[2*c+1], s0);
            s1 = fmaf(v1[c].x, w[2*c], s1); s1 = fmaf(v1[c].y, w[2*c+1], s1);
        }
        acc += fmaxf(s0, 0.f) + fmaxf(s1, 0.f);
    }
    if (p < end) {
        const f32x2* r0 = (const f32x2*)(pf + (size_t)p * F_P);
        float s0 = bias;
        #pragma unroll
        for (int c = 0; c < 7; ++c) {
            f32x2 v = __builtin_nontemporal_load(r0 + c);
            s0 = fmaf(v.x, w[2*c], s0); s0 = fmaf(v.y, w[2*c+1], s0);
        }
        acc += fmaxf(s0, 0.f);
    }
    if (lane < H) PA[(size_t)atom * H + lane] = acc;
}

// ---------------- kernel 3: A = relu([AA|PA] @ W_A + b_A) ----------------
__global__ __launch_bounds__(256) void k_atom_out(
    const float* __restrict__ AA, const float* __restrict__ PA,
    const float* __restrict__ W_A, const float* __restrict__ b_A,
    float* __restrict__ outA)
{
    __shared__ float sW[2 * H * H];
    __shared__ float sb[H];
    for (int t = threadIdx.x; t < 2 * H * H; t += 256) sW[t] = W_A[t];
    if (threadIdx.x < H) sb[threadIdx.x] = b_A[threadIdx.x];
    __syncthreads();

    const int wave = __builtin_amdgcn_readfirstlane(threadIdx.x >> 6);
    const int lane = threadIdx.x & 63;
    const int h = lane < H ? lane : 0;
    const int base = blockIdx.x * 32 + wave * 8;

    float acc[8];
    #pragma unroll
    for (int a = 0; a < 8; ++a) acc[a] = sb[h];

    for (int k = 0; k < H; ++k) {
        float wA = sW[k * H + h];
        float wP = sW[(H + k) * H + h];
        #pragma unroll
        for (int a = 0; a < 8; ++a) {
            acc[a] = fmaf(AA[(size_t)(base + a) * H + k], wA, acc[a]);
            acc[a] = fmaf(PA[(size_t)(base + a) * H + k], wP, acc[a]);
        }
    }
    #pragma unroll
    for (int a = 0; a < 8; ++a)
        if (lane < H) outA[(size_t)(base + a) * H + lane] = fmaxf(acc[a], 0.f);
}

// ---------------- kernel 4: P = relu([AP|PP] @ W_P + b_P) ----------------
__global__ __launch_bounds__(256) void k_pair_out(
    const float* __restrict__ pf, const int* __restrict__ a2p,
    const unsigned short* __restrict__ X,
    const float* __restrict__ b_AP, const float* __restrict__ W_PP,
    const float* __restrict__ b_PP, const float* __restrict__ W_P,
    const float* __restrict__ b_P, float* __restrict__ outP)
{
    __shared__ float sWpA[56][52];   // W_P rows 0..49 (AP part), zero-padded k>=50
    __shared__ float sWpP[H][52];    // W_P rows 50..99 (PP part)
    __shared__ float sWPP[F_P][52];
    __shared__ float sbAP[64], sbPP[64], sbP[64];

    for (int t = threadIdx.x; t < 56 * 52; t += 256) {
        int k = t / 52, hh = t % 52;
        sWpA[k][hh] = (k < H && hh < H) ? W_P[k * H + hh] : 0.f;
    }
    for (int t = threadIdx.x; t < H * 52; t += 256) {
        int k = t / 52, hh = t % 52;
        sWpP[k][hh] = (hh < H) ? W_P[(H + k) * H + hh] : 0.f;
    }
    for (int t = threadIdx.x; t < F_P * 52; t += 256) {
        int c = t / 52, hh = t % 52;
        sWPP[c][hh] = (hh < H) ? W_PP[c * H + hh] : 0.f;
    }
    if (threadIdx.x < 64) {
        sbAP[threadIdx.x] = threadIdx.x < H ? b_AP[threadIdx.x] : 0.f;
        sbPP[threadIdx.x] = threadIdx.x < H ? b_PP[threadIdx.x] : 0.f;
        sbP[threadIdx.x]  = threadIdx.x < H ? b_P[threadIdx.x]  : 0.f;
    }
    __syncthreads();

    const int p = blockIdx.x * 256 + threadIdx.x;
    const int2 ij = ((const int2*)a2p)[p];
    const uint4* rowi = (const uint4*)(X + (size_t)ij.x * 128);
    const uint4* rowj = (const uint4*)(X + (size_t)ij.y * 128);

    float acc[H];
    #pragma unroll
    for (int hh = 0; hh < H; ++hh) acc[hh] = sbP[hh];

    // ---- PP part (independent of gathers; gives loads time to land) ----
    float pfr[F_P];
    {
        const f32x2* src = (const f32x2*)(pf + (size_t)p * F_P);
        #pragma unroll
        for (int c = 0; c < 7; ++c) {
            f32x2 v = __builtin_nontemporal_load(src + c);
            pfr[2*c] = v.x; pfr[2*c+1] = v.y;
        }
    }
    for (int h2 = 0; h2 < H; ++h2) {
        float v = sbPP[h2];
        #pragma unroll
        for (int c = 0; c < F_P; ++c) v = fmaf(pfr[c], sWPP[c][h2], v);
        v = fmaxf(v, 0.f);
        #pragma unroll
        for (int hh = 0; hh < H; ++hh) acc[hh] = fmaf(v, sWpP[h2][hh], acc[hh]);
    }

    // ---- AP part: 7 chunks of 8 k-values, bf16 gathers ----
    #pragma unroll 2
    for (int c = 0; c < 7; ++c) {
        uint4 x1i = rowi[c], x2i = rowi[8 + c];
        uint4 x1j = rowj[c], x2j = rowj[8 + c];
        const unsigned* a1 = (const unsigned*)&x1i;
        const unsigned* a2 = (const unsigned*)&x2i;
        const unsigned* b1 = (const unsigned*)&x1j;
        const unsigned* b2 = (const unsigned*)&x2j;
        #pragma unroll
        for (int t = 0; t < 8; ++t) {
            int k = c * 8 + t;
            float e1 = bfu(a1[t >> 1], t & 1) + bfu(b2[t >> 1], t & 1) + sbAP[k];
            float e2 = bfu(b1[t >> 1], t & 1) + bfu(a2[t >> 1], t & 1) + sbAP[k];
            float ap = fmaxf(e1, 0.f) + fmaxf(e2, 0.f);
            #pragma unroll
            for (int hh = 0; hh < H; ++hh) acc[hh] = fmaf(ap, sWpA[k][hh], acc[hh]);
        }
    }

    float* dst = outP + (size_t)p * H;
    #pragma unroll
    for (int hh = 0; hh < H; hh += 2) {
        f32x2 v; v.x = fmaxf(acc[hh], 0.f); v.y = fmaxf(acc[hh + 1], 0.f);
        __builtin_nontemporal_store(v, (f32x2*)(dst + hh));
    }
}

// ---------------- launcher ----------------
extern "C" void kernel_launch(void* const* d_in, const int* in_sizes, int n_in,
                              void* d_out, int out_size, void* d_ws, size_t ws_size,
                              hipStream_t stream) {
    const float* af    = (const float*)d_in[0];
    const float* pfeat = (const float*)d_in[1];
    const int*   split = (const int*)d_in[2];
    const int*   a2p   = (const int*)d_in[3];
    const float* W_AA  = (const float*)d_in[4];
    const float* b_AA  = (const float*)d_in[5];
    const float* W_PA  = (const float*)d_in[6];
    const float* b_PA  = (const float*)d_in[7];
    const float* W_A   = (const float*)d_in[8];
    const float* b_A   = (const float*)d_in[9];
    const float* W_AP  = (const float*)d_in[10];
    const float* b_AP  = (const float*)d_in[11];
    const float* W_PP  = (const float*)d_in[12];
    const float* b_PP  = (const float*)d_in[13];
    const float* W_P   = (const float*)d_in[14];
    const float* b_P   = (const float*)d_in[15];

    float* outA = (float*)d_out;
    float* outP = (float*)d_out + (size_t)N_ATOMS * H;

    unsigned short* X  = (unsigned short*)d_ws;              // 100000*128*2B = 25.6MB
    float* AA          = (float*)(X + (size_t)N_ATOMS * 128);// 20MB
    float* PA          = AA + (size_t)N_ATOMS * H;           // 20MB
    int*   row_start   = (int*)(PA + (size_t)N_ATOMS * H);   // (N_ATOMS+1)*4B

    k_row_starts<<<(N_PAIRS + 255) / 256, 256, 0, stream>>>(split, row_start);
    k_atom_proj<<<N_ATOMS / 32, 256, 0, stream>>>(af, W_AA, b_AA, W_AP, AA, X);
    k_pa_segsum<<<N_ATOMS / 4, 256, 0, stream>>>(pfeat, row_start, W_PA, b_PA, PA);
    k_atom_out<<<N_ATOMS / 32, 256, 0, stream>>>(AA, PA, W_A, b_A, outA);
    k_pair_out<<<N_PAIRS / 256, 256, 0, stream>>>(pfeat, a2p, X,
                                                  b_AP, W_PP, b_PP, W_P, b_P, outP);
}